// Round 1
// baseline (1238.568 us; speedup 1.0000x reference)
//
#include <hip/hip_runtime.h>
#include <math.h>

#define TAU 0.07f
#define B_ 8
#define C_ 128
#define HW_ (512 * 512)
#define K_ 64
#define NNEG_ 7
#define P_ 4096

__device__ inline float wave_reduce_sum(float v) {
    #pragma unroll
    for (int off = 32; off; off >>= 1) v += __shfl_xor(v, off, 64);
    return v;
}

__device__ inline unsigned long long wave_reduce_maxu64(unsigned long long v) {
    #pragma unroll
    for (int off = 32; off; off >>= 1) {
        unsigned long long o = __shfl_xor(v, off, 64);
        v = (o > v) ? o : v;
    }
    return v;
}

// One block (128 threads) per prototype: L2-normalize pos_pool rows into ws.
__global__ void normalize_pool_kernel(const float* __restrict__ pool,
                                      float* __restrict__ pool_norm) {
    const int p = blockIdx.x;
    const int c = threadIdx.x;  // 128 threads
    __shared__ float red[2];
    float v = pool[p * C_ + c];
    float ws = wave_reduce_sum(v * v);
    const int wid = c >> 6;
    if ((c & 63) == 0) red[wid] = ws;
    __syncthreads();
    const float total = red[0] + red[1];
    const float inv = 1.0f / fmaxf(sqrtf(total), 1e-12f);
    pool_norm[p * C_ + c] = v * inv;
}

// One block (256 threads) per (b,k) query.
__global__ void __launch_bounds__(256)
loss_kernel(const float* __restrict__ qf,        // [B, C, HW]
            const float* __restrict__ pool_norm, // [P, C] unit rows
            const float* __restrict__ neg,       // [B, K, N, C]
            const int* __restrict__ qidx,        // [B, K]
            float* __restrict__ out) {
    const int bk = blockIdx.x;       // b*K + k
    const int b = bk >> 6;           // / K_
    const int t = threadIdx.x;
    const int wid = t >> 6;

    __shared__ __align__(16) float qn[C_];
    __shared__ float red[8];
    __shared__ unsigned long long redk[4];

    // ---- gather query pixel and L2-normalize ----
    const int idx = qidx[bk];
    float v = 0.0f;
    if (t < C_) v = qf[((size_t)b * C_ + t) * (size_t)HW_ + idx];
    {
        float ws = wave_reduce_sum(v * v);
        if ((t & 63) == 0) red[wid] = ws;
    }
    __syncthreads();
    const float qss = red[0] + red[1] + red[2] + red[3];
    const float qinv = 1.0f / fmaxf(sqrtf(qss), 1e-12f);
    if (t < C_) qn[t] = v * qinv;
    __syncthreads();

    // ---- argmax over P prototypes (thread-strided, fp32 float4 dots) ----
    const float4* __restrict__ pn4 = (const float4*)pool_norm;
    const float4* qn4 = (const float4*)qn;
    float best = -3.0e38f;
    int bestp = 0;
    for (int p = t; p < P_; p += 256) {
        const float4* row = pn4 + (size_t)p * (C_ / 4);
        float d = 0.0f;
        #pragma unroll
        for (int i = 0; i < C_ / 4; ++i) {
            float4 a = qn4[i];
            float4 r = row[i];
            d += a.x * r.x + a.y * r.y + a.z * r.z + a.w * r.w;
        }
        if (d > best) { best = d; bestp = p; }  // strict > keeps lowest p on tie
    }
    // pack (value, ~idx) so max-key == (max value, lowest index)
    unsigned int fu = __float_as_uint(best);
    fu = (fu & 0x80000000u) ? ~fu : (fu | 0x80000000u);
    unsigned long long key =
        ((unsigned long long)fu << 32) | (unsigned int)(~(unsigned int)bestp);
    key = wave_reduce_maxu64(key);
    if ((t & 63) == 0) redk[wid] = key;
    __syncthreads();
    if (t == 0) {
        unsigned long long k2 = redk[0];
        #pragma unroll
        for (int i = 1; i < 4; ++i) k2 = (redk[i] > k2) ? redk[i] : k2;
        redk[0] = k2;
    }
    __syncthreads();
    const unsigned long long fkey = redk[0];
    unsigned int vu = (unsigned int)(fkey >> 32);
    vu = (vu & 0x80000000u) ? (vu ^ 0x80000000u) : ~vu;
    const float posdot = __uint_as_float(vu);  // q_norm . pool_norm[pos_idx]

    // ---- negatives: 7 block reductions (sumsq + dot simultaneously) ----
    float lg[1 + NNEG_];
    lg[0] = posdot / TAU;
    const float qv = (t < C_) ? qn[t] : 0.0f;
    for (int n = 0; n < NNEG_; ++n) {
        float nv = 0.0f;
        if (t < C_) nv = neg[((size_t)bk * NNEG_ + n) * C_ + t];
        float s1 = wave_reduce_sum(nv * nv);
        float s2 = wave_reduce_sum(nv * qv);
        if ((t & 63) == 0) { red[wid] = s1; red[4 + wid] = s2; }
        __syncthreads();
        if (t == 0) {
            const float nss = red[0] + red[1] + red[2] + red[3];
            const float ndot = red[4] + red[5] + red[6] + red[7];
            lg[1 + n] = (ndot / fmaxf(sqrtf(nss), 1e-12f)) / TAU;
        }
        __syncthreads();
    }

    // ---- log-softmax CE, label 0; mean over B*K via atomic ----
    if (t == 0) {
        float m = lg[0];
        #pragma unroll
        for (int i = 1; i <= NNEG_; ++i) m = fmaxf(m, lg[i]);
        float se = 0.0f;
        #pragma unroll
        for (int i = 0; i <= NNEG_; ++i) se += expf(lg[i] - m);
        const float loss = (m + logf(se)) - lg[0];
        atomicAdd(out, loss * (1.0f / (B_ * K_)));
    }
}

extern "C" void kernel_launch(void* const* d_in, const int* in_sizes, int n_in,
                              void* d_out, int out_size, void* d_ws, size_t ws_size,
                              hipStream_t stream) {
    const float* query_feat = (const float*)d_in[0];  // [B, C, H, W] fp32
    const float* pos_pool   = (const float*)d_in[1];  // [P, C] fp32
    const float* neg_protos = (const float*)d_in[2];  // [B, K, N, C] fp32
    const int*   query_idx  = (const int*)d_in[3];    // [B, K] int32
    float* out = (float*)d_out;                       // scalar fp32

    float* pool_norm = (float*)d_ws;  // P*C floats = 2 MB

    hipMemsetAsync(out, 0, sizeof(float) * out_size, stream);
    normalize_pool_kernel<<<P_, C_, 0, stream>>>(pos_pool, pool_norm);
    loss_kernel<<<B_ * K_, 256, 0, stream>>>(query_feat, pool_norm, neg_protos,
                                             query_idx, out);
}